// Round 6
// baseline (235.568 us; speedup 1.0000x reference)
//
#include <hip/hip_runtime.h>
#include <hip/hip_bf16.h>

#define BB 8
#define NN 2048
#define FIN 128
#define FO 64
#define ALPHA 0.2f

typedef __attribute__((ext_vector_type(8))) short bf16x8;
typedef __attribute__((ext_vector_type(4))) float f32x4;
typedef __attribute__((ext_vector_type(4))) int i32x4;

typedef __attribute__((address_space(1))) const void gvoid;
typedef __attribute__((address_space(3))) void lvoid;

__device__ inline void gl_lds4(const void* g, void* l) {
    // async global->LDS, 4B per lane; LDS dest = uniform base + lane*4
    __builtin_amdgcn_global_load_lds((gvoid*)g, (lvoid*)l, 4, 0, 0);
}

__device__ inline short f2bf(float x) {
    unsigned u = __float_as_uint(x);
    u += 0x7fffu + ((u >> 16) & 1u);   // RNE, sign-agnostic, no NaN inputs here
    return (short)(u >> 16);
}

// ---------------- Kernel A: Wh = h@W; whF in MFMA B-fragment layout ----------
// whF[b][jc][ot][lane][8] shorts: lane L holds Wh[b][j=jc*32+(L>>4)*8+jj][o=ot*16+(L&15)]
// h rows are wave-uniform -> scalar (K$) loads; no LDS, no barrier.
// e2 maxes: ONE non-atomic float store per wave into e2p[b][0..255].
__global__ __launch_bounds__(256) void wh_kernel(
    const float* __restrict__ h, const float* __restrict__ W,
    const float* __restrict__ a, float* __restrict__ e1, float* __restrict__ e2,
    float* __restrict__ e2p, short* __restrict__ whF)
{
    const int t  = threadIdx.x;
    const int o  = t & 63;
    const int wv = t >> 6;                     // rows wv*8 .. wv*8+7
    const int r0 = blockIdx.x * 32;            // 32 rows per block (same batch)
    const float* __restrict__ hrow =
        h + (size_t)(r0 + __builtin_amdgcn_readfirstlane(wv) * 8) * FIN;

    float acc[8];
#pragma unroll
    for (int rr = 0; rr < 8; rr++) acc[rr] = 0.f;

    for (int f = 0; f < FIN; f += 4) {
        const float w0 = W[(f + 0) * FO + o];
        const float w1 = W[(f + 1) * FO + o];
        const float w2 = W[(f + 2) * FO + o];
        const float w3 = W[(f + 3) * FO + o];
#pragma unroll
        for (int rr = 0; rr < 8; rr++) {
            const float4 hv = *(const float4*)(hrow + rr * FIN + f);  // uniform -> SGPR
            acc[rr] = fmaf(hv.x, w0, acc[rr]);
            acc[rr] = fmaf(hv.y, w1, acc[rr]);
            acc[rr] = fmaf(hv.z, w2, acc[rr]);
            acc[rr] = fmaf(hv.w, w3, acc[rr]);
        }
    }

    const int b   = r0 / NN;
    const int ib0 = r0 - b * NN;
    const int ibb = ib0 + wv * 8;
    const int jc  = ibb >> 5;
    const int qq  = (ibb >> 3) & 3;
    const int ot  = o >> 4, mm = o & 15;
    const int L   = mm + qq * 16;
    bf16x8 frag;
#pragma unroll
    for (int rr = 0; rr < 8; rr++) frag[rr] = f2bf(acc[rr]);
    *(bf16x8*)(whF + ((((size_t)(b * 64 + jc) * 4 + ot) * 64 + L) * 8)) = frag;

    const float a1 = a[o], a2 = a[FO + o];
    float vmax = -3.0e38f;
#pragma unroll
    for (int rr = 0; rr < 8; rr++) {
        float v1 = acc[rr] * a1, v2 = acc[rr] * a2;
#pragma unroll
        for (int msk = 32; msk >= 1; msk >>= 1) {
            v1 += __shfl_xor(v1, msk, 64);
            v2 += __shfl_xor(v2, msk, 64);
        }
        vmax = fmaxf(vmax, v2);
        if (o == 0) { e1[r0 + wv * 8 + rr] = v1; e2[r0 + wv * 8 + rr] = v2; }
    }
    if (o == 0) e2p[b * 256 + (ib0 >> 5) * 4 + wv] = vmax;
}

// ---------------- Kernel B: staged attention, deep counted-vmcnt pipeline ----
// R5 post-mortem: register-resident adj mixed short-latency whF loads and
// long-latency adj loads in ONE in-order vmcnt queue -> consuming whF drained
// 2-3-step-old adj (<900cy) every step.  Fix: back to gl_lds STAGING (decouples
// adj from register consumption) with correct leads:
//   adj: 4 LDS buffers, staged 3 tiles ahead (~2400cy lead >> 900cy HBM)
//   whF/e2: register dbuf, 1 tile ahead (~800cy lead >> ~300cy L2)
// Per tile: vmcnt(X) [hand-counted, NEVER 0] -> s_barrier -> wh(t+1) ->
// stage(t+3) -> compute(t).  wh issued BEFORE stage each tile, so the
// compiler's wait for wh(t) (vmcnt(22)) leaves all unretired stages in flight.
// In steady state every wait targets an already-retired load.
// LDS: adj[4][16][132] ints = 33.8KB (row pad 132 keeps banks balanced; pad
// lives BETWEEN rows so per-row gl_lds stays contiguous) -> 4 blocks/CU.
struct SMemS { int adj[4][16][132]; };
struct SMemC { float comb[4][16][64]; float lsum[4][16]; };
union __align__(16) SMemU { SMemS s; SMemC c; };

#define TILE(T, XW) do {                                                       \
    asm volatile("s_waitcnt vmcnt(" #XW ")" ::: "memory");                     \
    __builtin_amdgcn_s_barrier();                                              \
    if ((T) < 15) {                                                            \
        const short* bfp = whFb + (size_t)(((T) + 1) * 4 + w) * 2048 + lane * 8;\
        wb[((T) + 1) & 1][0] = *(const bf16x8*)(bfp);                          \
        wb[((T) + 1) & 1][1] = *(const bf16x8*)(bfp + 512);                    \
        wb[((T) + 1) & 1][2] = *(const bf16x8*)(bfp + 1024);                   \
        wb[((T) + 1) & 1][3] = *(const bf16x8*)(bfp + 1536);                   \
        const float* ew = e2b + ((T) + 1) * 128 + w * 32 + q * 8;              \
        eb[((T) + 1) & 1][0] = *(const f32x4*)(ew);                            \
        eb[((T) + 1) & 1][1] = *(const f32x4*)(ew + 4);                        \
    }                                                                          \
    asm volatile("" ::: "memory");      /* wh older than stage in queue */     \
    if ((T) <= 12) {                                                           \
        _Pragma("unroll")                                                      \
        for (int rr = 0; rr < 4; rr++) {                                       \
            gl_lds4(astage + (size_t)rr * NN + ((T) + 3) * 128,                \
                    &sm.s.adj[((T) + 3) & 3][w * 4 + rr][0]);                  \
            gl_lds4(astage + (size_t)rr * NN + ((T) + 3) * 128 + 64,           \
                    &sm.s.adj[((T) + 3) & 3][w * 4 + rr][64]);                 \
        }                                                                      \
    }                                                                          \
    asm volatile("" ::: "memory");                                             \
    {                                                                          \
        i32x4 a0 = *(const i32x4*)&sm.s.adj[(T) & 3][m][w * 32 + q * 8];       \
        i32x4 a1 = *(const i32x4*)&sm.s.adj[(T) & 3][m][w * 32 + q * 8 + 4];   \
        bf16x8 af;                                                             \
        _Pragma("unroll")                                                      \
        for (int jj = 0; jj < 8; jj++) {                                       \
            const int   av  = (jj < 4) ? a0[jj] : a1[jj - 4];                  \
            const float e2j = (jj < 4) ? eb[(T) & 1][0][jj]                    \
                                       : eb[(T) & 1][1][jj - 4];               \
            float e = e1v + e2j;                                               \
            e = e > 0.f ? e : ALPHA * e;                                       \
            const float pe = (av > 0) ? __expf(e - mi) : 0.f;                  \
            lsum += pe;                                                        \
            af[jj] = f2bf(pe);                                                 \
        }                                                                      \
        acc0 = __builtin_amdgcn_mfma_f32_16x16x32_bf16(af, wb[(T) & 1][0], acc0, 0, 0, 0); \
        acc1 = __builtin_amdgcn_mfma_f32_16x16x32_bf16(af, wb[(T) & 1][1], acc1, 0, 0, 0); \
        acc2 = __builtin_amdgcn_mfma_f32_16x16x32_bf16(af, wb[(T) & 1][2], acc2, 0, 0, 0); \
        acc3 = __builtin_amdgcn_mfma_f32_16x16x32_bf16(af, wb[(T) & 1][3], acc3, 0, 0, 0); \
    }                                                                          \
} while (0)

__global__ __launch_bounds__(256, 4) void attn_kernel(
    const int* __restrict__ adj, const float* __restrict__ e1,
    const float* __restrict__ e2, const float* __restrict__ e2p,
    const short* __restrict__ whF, float* __restrict__ out)
{
    __shared__ SMemU sm;
    __shared__ float red4[4];                  // outside union: no alias games
    const int t = threadIdx.x, w = t >> 6, lane = t & 63;
    const int m = lane & 15, q = lane >> 4;
    const int blk = blockIdx.x;
    const int b  = blk >> 7;
    const int i0 = (blk & 127) * 16;
    const int i  = i0 + m;

    // ---- batch e2max from per-wave partials (256 floats, L2-resident) ----
    float pv = e2p[b * 256 + t];
    const float e1v = e1[b * NN + i];
#pragma unroll
    for (int k = 32; k >= 1; k >>= 1) pv = fmaxf(pv, __shfl_xor(pv, k, 64));
    if (lane == 0) red4[w] = pv;
    __syncthreads();                           // before ANY staging: drains nothing hot
    const float e2mx = fmaxf(fmaxf(red4[0], red4[1]), fmaxf(red4[2], red4[3]));

    float mi = e1v + e2mx;
    mi = mi > 0.f ? mi : ALPHA * mi;           // safe per-row max bound (leakyrelu monotone)

    const short* whFb = whF + (size_t)b * (64 * 4 * 64 * 8);
    const float* e2b = e2 + b * NN;
    // staging source: wave w owns rows w*4..w*4+3; lane reads 1 int (gl_lds size 4)
    const int* astage = adj + (size_t)(b * NN + i0 + w * 4) * NN + lane;

    f32x4 acc0 = {0.f,0.f,0.f,0.f}, acc1 = acc0, acc2 = acc0, acc3 = acc0;
    float lsum = 0.f;

    bf16x8 wb[2][4];           // whF register dbuf (1-tile lead)
    f32x4  eb[2][2];           // e2 register dbuf

    // prologue: wh(0)/e2(0) FIRST (older than all stages), then stage tiles 0..2
    {
        const short* bfp = whFb + (size_t)w * 2048 + lane * 8;
        wb[0][0] = *(const bf16x8*)(bfp);
        wb[0][1] = *(const bf16x8*)(bfp + 512);
        wb[0][2] = *(const bf16x8*)(bfp + 1024);
        wb[0][3] = *(const bf16x8*)(bfp + 1536);
        const float* ew = e2b + w * 32 + q * 8;
        eb[0][0] = *(const f32x4*)(ew);
        eb[0][1] = *(const f32x4*)(ew + 4);
    }
    asm volatile("" ::: "memory");
#pragma unroll
    for (int tt = 0; tt < 3; tt++) {
#pragma unroll
        for (int rr = 0; rr < 4; rr++) {
            gl_lds4(astage + (size_t)rr * NN + tt * 128, &sm.s.adj[tt][w * 4 + rr][0]);
            gl_lds4(astage + (size_t)rr * NN + tt * 128 + 64, &sm.s.adj[tt][w * 4 + rr][64]);
        }
    }
    asm volatile("" ::: "memory");

    // hand-counted vmcnt per tile = #loads issued after stage(T):
    // T0: stage(1)+stage(2)=16.  T1: stage(2)+wh(1)+stage(3)=22.
    // T2..13: wh+stage twice = 28.  T14: 8+6+6=20.  T15: 6+6=12.
    TILE(0, 16);  TILE(1, 22);  TILE(2, 28);  TILE(3, 28);
    TILE(4, 28);  TILE(5, 28);  TILE(6, 28);  TILE(7, 28);
    TILE(8, 28);  TILE(9, 28);  TILE(10, 28); TILE(11, 28);
    TILE(12, 28); TILE(13, 28); TILE(14, 20); TILE(15, 12);

    // all waves done with LDS adj buffers before the union flips to combine
    __syncthreads();

    // cross-wave combine in LDS (each wave saw a disjoint jc set)
    lsum += __shfl_xor(lsum, 16, 64);
    lsum += __shfl_xor(lsum, 32, 64);
    if (q == 0) sm.c.lsum[w][m] = lsum;
#pragma unroll
    for (int ot = 0; ot < 4; ot++) {
        f32x4 av = (ot == 0) ? acc0 : (ot == 1) ? acc1 : (ot == 2) ? acc2 : acc3;
#pragma unroll
        for (int reg = 0; reg < 4; reg++)
            sm.c.comb[w][q * 4 + reg][ot * 16 + m] = av[reg];
    }
    __syncthreads();

    const int row = t >> 4, c0 = (t & 15) * 4;
    f32x4 sum = *(const f32x4*)&sm.c.comb[0][row][c0];
#pragma unroll
    for (int ww = 1; ww < 4; ww++) {
        f32x4 sv = *(const f32x4*)&sm.c.comb[ww][row][c0];
        sum.x += sv.x; sum.y += sv.y; sum.z += sv.z; sum.w += sv.w;
    }
    float l = sm.c.lsum[0][row] + sm.c.lsum[1][row] + sm.c.lsum[2][row] + sm.c.lsum[3][row];
    l = fmaxf(l, 1e-30f);
    const float rl = 1.f / l;
    float vr[4] = { sum.x * rl, sum.y * rl, sum.z * rl, sum.w * rl };
    f32x4 res;
#pragma unroll
    for (int kk = 0; kk < 4; kk++)
        res[kk] = vr[kk] > 0.f ? vr[kk] : (__expf(vr[kk]) - 1.f);
    *(f32x4*)&out[((size_t)(b * NN + i0 + row)) * FO + c0] = res;
}

extern "C" void kernel_launch(void* const* d_in, const int* in_sizes, int n_in,
                              void* d_out, int out_size, void* d_ws, size_t ws_size,
                              hipStream_t stream) {
    const float* h   = (const float*)d_in[0];
    const int*   adj = (const int*)d_in[1];
    const float* W   = (const float*)d_in[2];
    const float* a   = (const float*)d_in[3];
    float* out = (float*)d_out;

    char* ws = (char*)d_ws;
    short* whF = (short*)ws;                                   // 2 MB
    size_t off = (size_t)BB * 64 * 4 * 64 * 8 * sizeof(short);
    float* e1  = (float*)(ws + off);  off += (size_t)BB * NN * 4;
    float* e2  = (float*)(ws + off);  off += (size_t)BB * NN * 4;
    float* e2p = (float*)(ws + off);                           // 8 x 256 partial maxes

    wh_kernel<<<(BB * NN) / 32, 256, 0, stream>>>(h, W, a, e1, e2, e2p, whF);
    attn_kernel<<<BB * (NN / 16), 256, 0, stream>>>(adj, e1, e2, e2p, whF, out);
}